// Round 2
// baseline (397.122 us; speedup 1.0000x reference)
//
#include <hip/hip_runtime.h>
#include <hip/hip_bf16.h>
#include <stdint.h>

// Problem (all fp32 I/O): out[m,o] = sum_k x[m,k] * qw[o,k] + bias[o]
//   qw = ternarize(weight): scale_o = max(max_k |w[o,k]|, 1e-6);
//   t = (w/scale > .5 ? 1 : w/scale < -.5 ? -1 : 0); qw = t*scale.
// Ternary t is exact in bf16; scale stays fp32 and is applied in the GEMM
// epilogue. x is converted fp32->bf16 once (error ~0.009 max, threshold .079).
// M=16384 (B*S), N=2048 (D_out), K=2048 (D_in).

#define M_DIM 16384
#define N_DIM 2048
#define K_DIM 2048

#define BM 128
#define BN 128
#define BK 32

typedef __bf16 bf16x8 __attribute__((ext_vector_type(8)));
typedef float f32x4 __attribute__((ext_vector_type(4)));

// ---------------------------------------------------------------------------
// Pass A: x fp32 -> bf16. 8 elements/thread, float4 loads, 16 B store.
// ---------------------------------------------------------------------------
__global__ __launch_bounds__(256) void cvt_x_k(
    const float* __restrict__ x, __hip_bfloat16* __restrict__ xb) {
  const size_t i = ((size_t)blockIdx.x * 256 + threadIdx.x) * 8;
  const float4 a = *(const float4*)(x + i);
  const float4 b = *(const float4*)(x + i + 4);
  bf16x8 o;
  o[0] = (__bf16)a.x; o[1] = (__bf16)a.y; o[2] = (__bf16)a.z; o[3] = (__bf16)a.w;
  o[4] = (__bf16)b.x; o[5] = (__bf16)b.y; o[6] = (__bf16)b.z; o[7] = (__bf16)b.w;
  *(bf16x8*)((__bf16*)xb + i) = o;
}

// ---------------------------------------------------------------------------
// Pass B: per-row ternarize (fp32 in, bf16 ternary out, fp32 scale).
// One block per output row.
// ---------------------------------------------------------------------------
__global__ __launch_bounds__(256) void ternarize_k(
    const float* __restrict__ w,
    __hip_bfloat16* __restrict__ qw,
    float* __restrict__ scales) {
  const int row = blockIdx.x;
  const float* wr = w + (size_t)row * K_DIM;

  float m = 0.0f;
  for (int k = threadIdx.x; k < K_DIM; k += 256)
    m = fmaxf(m, fabsf(wr[k]));

  for (int off = 32; off > 0; off >>= 1)
    m = fmaxf(m, __shfl_down(m, off, 64));
  __shared__ float wmax[4];
  if ((threadIdx.x & 63) == 0) wmax[threadIdx.x >> 6] = m;
  __syncthreads();
  float scale = fmaxf(fmaxf(wmax[0], wmax[1]), fmaxf(wmax[2], wmax[3]));
  scale = fmaxf(scale, 1e-6f);
  if (threadIdx.x == 0) scales[row] = scale;

  for (int k = threadIdx.x; k < K_DIM; k += 256) {
    const float v = wr[k] / scale;  // identical fp32 op to the reference
    const float t = (v > 0.5f) ? 1.0f : ((v < -0.5f) ? -1.0f : 0.0f);
    qw[(size_t)row * K_DIM + k] = __float2bfloat16(t);
  }
}

// ---------------------------------------------------------------------------
// Pass C: bf16 MFMA GEMM (m97 structure). A = xb [M,K], B = qw [N,K] (B^T
// layout). Block tile 128x128, BK=32, 256 threads = 4 waves in 2x2, each wave
// 64x64 via 4x4 grid of 16x16x32 MFMAs. global_load_lds width=16 staging.
// fp32 epilogue: C = acc*scale[n] + bias[n].
// ---------------------------------------------------------------------------
static __device__ __forceinline__ void async_cp16(const __hip_bfloat16* g,
                                                  __hip_bfloat16* l) {
  __builtin_amdgcn_global_load_lds(
      (__attribute__((address_space(1))) void*)const_cast<__hip_bfloat16*>(g),
      (__attribute__((address_space(3))) void*)(l), 16, 0, 0);
}

__global__ __launch_bounds__(256) void gemm_bt_k(
    const __hip_bfloat16* __restrict__ A,     // xb  [M,K] bf16
    const __hip_bfloat16* __restrict__ B,     // qw  [N,K] bf16 ternary
    const float* __restrict__ scales,         // [N] fp32
    const float* __restrict__ bias,           // [N] fp32
    float* __restrict__ C) {                  // [M,N] fp32
  // No padding: global_load_lds dest is wave-uniform base + lane*16; LDS
  // layout must be contiguous in lane order.
  __shared__ __hip_bfloat16 As[BM * BK];  // 8 KB
  __shared__ __hip_bfloat16 Bs[BN * BK];  // 8 KB

  const int tid = threadIdx.x;
  const int wave = tid >> 6;
  const int lane = tid & 63;
  const int quad = lane >> 4;
  const int lrow = lane & 15;
  const int wm = wave >> 1;
  const int wn = wave & 1;

  const int m0 = blockIdx.y * BM;
  const int n0 = blockIdx.x * BN;

  // Tile = 128 rows x 64 B = 512 16-B chunks; thread tid does chunks tid and
  // tid+256. chunk c -> row c>>2, elem (c&3)*8. LDS byte offset = 16*c.
  const int c = tid;
  const __hip_bfloat16* Ag0 = A + (size_t)(m0 + (c >> 2)) * K_DIM + (c & 3) * 8;
  const __hip_bfloat16* Ag1 = A + (size_t)(m0 + ((c + 256) >> 2)) * K_DIM + (c & 3) * 8;
  const __hip_bfloat16* Bg0 = B + (size_t)(n0 + (c >> 2)) * K_DIM + (c & 3) * 8;
  const __hip_bfloat16* Bg1 = B + (size_t)(n0 + ((c + 256) >> 2)) * K_DIM + (c & 3) * 8;

  __hip_bfloat16* As_w0 = As + wave * 512;
  __hip_bfloat16* As_w1 = As + wave * 512 + 2048;
  __hip_bfloat16* Bs_w0 = Bs + wave * 512;
  __hip_bfloat16* Bs_w1 = Bs + wave * 512 + 2048;

  f32x4 acc[4][4] = {};

  for (int kk = 0; kk < K_DIM; kk += BK) {
    __syncthreads();  // previous tile fully consumed
    async_cp16(Ag0 + kk, As_w0);
    async_cp16(Ag1 + kk, As_w1);
    async_cp16(Bg0 + kk, Bs_w0);
    async_cp16(Bg1 + kk, Bs_w1);
    __syncthreads();  // compiler drains vmcnt(0) before s_barrier

    bf16x8 af[4], bfr[4];
    // A frag: A[m = lane&15][k = quad*8 + j] -> 16 B contiguous in LDS
    #pragma unroll
    for (int i = 0; i < 4; ++i)
      af[i] = *(const bf16x8*)(As + (wm * 64 + i * 16 + lrow) * BK + quad * 8);
    // B frag (B^T source): B[n = lane&15][k = quad*8 + j]
    #pragma unroll
    for (int i = 0; i < 4; ++i)
      bfr[i] = *(const bf16x8*)(Bs + (wn * 64 + i * 16 + lrow) * BK + quad * 8);

    #pragma unroll
    for (int i = 0; i < 4; ++i)
      #pragma unroll
      for (int j = 0; j < 4; ++j)
        acc[i][j] = __builtin_amdgcn_mfma_f32_16x16x32_bf16(af[i], bfr[j], acc[i][j], 0, 0, 0);
  }

  // Epilogue: C/D layout col = lane&15, row = quad*4 + reg (16x16x32 bf16).
  #pragma unroll
  for (int j = 0; j < 4; ++j) {
    const int col = n0 + wn * 64 + j * 16 + lrow;
    const float s = scales[col];
    const float b = bias[col];
    #pragma unroll
    for (int i = 0; i < 4; ++i) {
      const int rbase = m0 + wm * 64 + i * 16 + quad * 4;
      #pragma unroll
      for (int r = 0; r < 4; ++r)
        C[(size_t)(rbase + r) * N_DIM + col] = acc[i][j][r] * s + b;
    }
  }
}

extern "C" void kernel_launch(void* const* d_in, const int* in_sizes, int n_in,
                              void* d_out, int out_size, void* d_ws, size_t ws_size,
                              hipStream_t stream) {
  const float* x    = (const float*)d_in[0];  // [4,4096,2048] fp32
  const float* w    = (const float*)d_in[1];  // [2048,2048]   fp32
  const float* bias = (const float*)d_in[2];  // [2048]        fp32
  float* out = (float*)d_out;                 // [16384,2048]  fp32

  // ws layout: xb bf16 [M*K] (64 MiB) | qw bf16 [N*K] (8 MiB) | scales fp32 [N]
  __hip_bfloat16* xb = (__hip_bfloat16*)d_ws;
  __hip_bfloat16* qw = (__hip_bfloat16*)((char*)d_ws + (size_t)M_DIM * K_DIM * 2);
  float* scales = (float*)((char*)d_ws + (size_t)M_DIM * K_DIM * 2 + (size_t)N_DIM * K_DIM * 2);

  cvt_x_k<<<dim3((M_DIM * (size_t)K_DIM) / (256 * 8)), dim3(256), 0, stream>>>(x, xb);
  ternarize_k<<<dim3(N_DIM), dim3(256), 0, stream>>>(w, qw, scales);
  gemm_bt_k<<<dim3(N_DIM / BN, M_DIM / BM), dim3(256), 0, stream>>>(xb, qw, scales, bias, out);
}